// Round 4
// baseline (532.861 us; speedup 1.0000x reference)
//
#include <hip/hip_runtime.h>

#define DD 300
#define NT 19                       // staged n-tiles of 16 (covers 304)
#define NT2 24                      // frag-layout tiles (19 real + 5 zero pad)
#define NCH 10                      // k-chunks of 32
#define PLANE_SH 9728               // shorts per W plane-chunk in LDS: 19*512
#define WB_SH (2 * PLANE_SH)        // one LDS staging buffer (hi+lo) = 19456 shorts
#define WF2_PL (NCH * NT2 * 512)    // shorts per frag-layout plane = 122880
#define SROW_ST 312                 // shorts per s-row (16B aligned)
#define SPLANE_SH (64 * SROW_ST)    // shorts per s plane (64 rows)

typedef __attribute__((ext_vector_type(8))) short short8;
typedef __attribute__((ext_vector_type(4))) float f32x4;

__device__ __forceinline__ unsigned short bf16_rne(float x) {
    union { float f; unsigned u; } v; v.f = x;
    v.u += 0x7FFF + ((v.u >> 16) & 1);
    return (unsigned short)(v.u >> 16);
}
__device__ __forceinline__ float bf16_to_f32(unsigned short h) {
    union { unsigned u; float f; } v; v.u = (unsigned)h << 16;
    return v.f;
}
__device__ __forceinline__ void gload_lds16(const void* g, void* l) {
    __builtin_amdgcn_global_load_lds(
        (const __attribute__((address_space(1))) unsigned*)g,
        (__attribute__((address_space(3))) unsigned*)l, 16, 0, 0);
}

// W -> MFMA-fragment-ordered bf16 hi/lo planes, 24 tiles (19 real + 5 zero):
// Wf[pl][c][t][lane][i] = plane_pl of W[n=t*16+(lane&15)][k=c*32+(lane>>4)*8+i]
__global__ void split_w(const float* __restrict__ Wl, short* __restrict__ Wf) {
    int idx = blockIdx.x * 256 + threadIdx.x;
    if (idx >= WF2_PL) return;
    int i = idx & 7, lane = (idx >> 3) & 63, rest = idx >> 9;
    int t = rest % NT2, c = rest / NT2;
    int n = t * 16 + (lane & 15);
    int k = c * 32 + (lane >> 4) * 8 + i;
    float v = (n < DD && k < DD) ? Wl[n * DD + k] : 0.f;
    unsigned short hi = bf16_rne(v);
    Wf[idx] = (short)hi;
    Wf[idx + WF2_PL] = (short)bf16_rne(v - bf16_to_f32(hi));
}

__device__ __forceinline__ void out_store(float* out, int la, int g_row,
                                          float o0, float o1, float o2,
                                          const float* bp) {
    int lg = 12 - la;
    int offk = 8192 - (8192 >> la);
    int b = g_row >> lg, n2 = g_row & ((1 << lg) - 1);
    float* o = out + ((size_t)b * 8191 + offk + n2) * 3;
    o[0] = o0 + bp[0]; o[1] = o1 + bp[1]; o[2] = o2 + bp[2];
}

// ---------------- Kernel A: level-0 proj + level 1 only. LDS = wbuf only
// (76 KB) -> 2 blocks/CU, one block-round. Seam: f32 pairsums (64 rows/blk).
__global__ __launch_bounds__(512, 4) void tree_a(
    const float* __restrict__ emb, const int* __restrict__ ids,
    const short* __restrict__ Wf,
    const float* __restrict__ bl, const float* __restrict__ Wp,
    const float* __restrict__ bp, float* __restrict__ out,
    float* __restrict__ seam)
{
    __shared__ __align__(16) short wbuf[2 * WB_SH];
    const int tid = threadIdx.x;
    const int wid = tid >> 6, lane = tid & 63;
    const int r = lane & 15, q = lane >> 4;
    const int blk = blockIdx.x;

    auto stage = [&](int c, int bsel) {
        short* wb = &wbuf[bsel * WB_SH];
        #pragma unroll
        for (int t2i = 0; t2i < 5; ++t2i) {
            int t2 = wid + t2i * 8;
            if (t2 < 2 * NT) {
                int pl = t2 >= NT ? 1 : 0;
                int ss = t2 - pl * NT;
                gload_lds16(Wf + (long)pl * WF2_PL + ((long)c * NT2 + ss) * 512 + lane * 8,
                            &wb[pl * PLANE_SH + ss * 512]);
            }
        }
    };

    const int rowA = wid * 16 + r;
    long mA = (long)blk * 128 + rowA;
    const float* p0 = emb + (long)ids[2 * mA] * DD;
    const float* p1 = emb + (long)ids[2 * mA + 1] * DD;

    float pr[2][3] = {};
    f32x4 acc[NT];
    #pragma unroll
    for (int t = 0; t < NT; ++t)
        #pragma unroll
        for (int i = 0; i < 4; ++i) acc[t][i] = 0.f;

    f32x4 xc[4], xn[4];
    auto loadx = [&](int c, f32x4* x) {
        int kk = c * 32 + q * 8;
        if (kk + 8 <= DD) {
            x[0] = *(const f32x4*)(p0 + kk); x[1] = *(const f32x4*)(p0 + kk + 4);
            x[2] = *(const f32x4*)(p1 + kk); x[3] = *(const f32x4*)(p1 + kk + 4);
        } else {
            #pragma unroll
            for (int i = 0; i < 8; ++i) {
                int kg = kk + i;
                x[i >> 2][i & 3]       = (kg < DD) ? p0[kg] : 0.f;
                x[2 + (i >> 2)][i & 3] = (kg < DD) ? p1[kg] : 0.f;
            }
        }
    };

    stage(0, 0);
    loadx(0, xc);
    #pragma unroll 1
    for (int c = 0; c < NCH; ++c) {
        __syncthreads();
        if (c + 1 < NCH) { stage(c + 1, (c + 1) & 1); loadx(c + 1, xn); }
        f32x4 s0v = xc[0] + xc[2], s1v = xc[1] + xc[3];
        short8 xhi, xlo;
        #pragma unroll
        for (int i = 0; i < 4; ++i) {
            unsigned short h; float v;
            v = s0v[i]; h = bf16_rne(v); xhi[i]     = (short)h; xlo[i]     = (short)bf16_rne(v - bf16_to_f32(h));
            v = s1v[i]; h = bf16_rne(v); xhi[4 + i] = (short)h; xlo[4 + i] = (short)bf16_rne(v - bf16_to_f32(h));
        }
        {   // fused level-0 projection off the in-register gather
            int kk = c * 32 + q * 8;
            #pragma unroll
            for (int i = 0; i < 8; ++i) {
                int kg = kk + i;
                float w0 = (kg < DD) ? Wp[kg] : 0.f;
                float w1 = (kg < DD) ? Wp[DD + kg] : 0.f;
                float w2 = (kg < DD) ? Wp[2 * DD + kg] : 0.f;
                float xa = xc[i >> 2][i & 3];
                float xb = xc[2 + (i >> 2)][i & 3];
                pr[0][0] += xa * w0; pr[0][1] += xa * w1; pr[0][2] += xa * w2;
                pr[1][0] += xb * w0; pr[1][1] += xb * w1; pr[1][2] += xb * w2;
            }
        }
        const short8* bb = (const short8*)&wbuf[(c & 1) * WB_SH] + lane;
        #pragma unroll
        for (int t = 0; t < NT; ++t) {
            short8 bh = bb[t * 64];
            short8 bo = bb[1216 + t * 64];
            acc[t] = __builtin_amdgcn_mfma_f32_16x16x32_bf16(xhi, bh, acc[t], 0, 0, 0);
            acc[t] = __builtin_amdgcn_mfma_f32_16x16x32_bf16(xhi, bo, acc[t], 0, 0, 0);
            acc[t] = __builtin_amdgcn_mfma_f32_16x16x32_bf16(xlo, bh, acc[t], 0, 0, 0);
        }
        if (c + 1 < NCH) {
            #pragma unroll
            for (int i = 0; i < 4; ++i) xc[i] = xn[i];
        }
    }

    __syncthreads();
    float* pjb = (float*)wbuf;
    {
        float pj[4][3] = {};
        #pragma unroll
        for (int t = 0; t < NT; ++t) {
            int n = t * 16 + r;
            bool nok = n < DD;
            float w0 = nok ? Wp[n] : 0.f;
            float w1 = nok ? Wp[DD + n] : 0.f;
            float w2 = nok ? Wp[2 * DD + n] : 0.f;
            float b2 = nok ? 2.f * bl[n] : 0.f;
            float v[4];
            #pragma unroll
            for (int g = 0; g < 4; ++g) {
                float a = acc[t][g] + b2; v[g] = a > 0.f ? a : 0.f;
                pj[g][0] += v[g] * w0; pj[g][1] += v[g] * w1; pj[g][2] += v[g] * w2;
            }
            if (nok) {
                int sr = blk * 64 + wid * 8 + q * 2;
                seam[(size_t)sr * DD + n]       = v[0] + v[1];
                seam[(size_t)(sr + 1) * DD + n] = v[2] + v[3];
            }
        }
        #pragma unroll
        for (int g = 0; g < 4; ++g)
            #pragma unroll
            for (int cc = 0; cc < 3; ++cc)
                pjb[((wid * 16 + q * 4 + g) * 16 + r) * 3 + cc] = pj[g][cc];
    }
    __syncthreads();
    if (tid < 128) {
        const float* base = &pjb[tid * 48];
        float o0 = 0.f, o1 = 0.f, o2 = 0.f;
        #pragma unroll
        for (int rr = 0; rr < 16; ++rr) {
            o0 += base[rr * 3]; o1 += base[rr * 3 + 1]; o2 += base[rr * 3 + 2];
        }
        out_store(out, 1, blk * 128 + tid, o0, o1, o2, bp);
    }
    // level-0 projection finish
    #pragma unroll
    for (int j = 0; j < 2; ++j)
        #pragma unroll
        for (int cc = 0; cc < 3; ++cc) {
            float v = pr[j][cc];
            v += __shfl_xor(v, 16);
            v += __shfl_xor(v, 32);
            pr[j][cc] = v;
        }
    if (q == 0) {
        #pragma unroll
        for (int j = 0; j < 2; ++j) {
            long gr = 2 * mA + j;
            int b = (int)(gr >> 12), n = (int)(gr & 4095);
            float* o = out + ((size_t)b * 8191 + n) * 3;
            o[0] = pr[j][0] + bp[0];
            o[1] = pr[j][1] + bp[1];
            o[2] = pr[j][2] + bp[2];
        }
    }
}

// ---------------- tile-outer streamed level: acc = one f32x4 per tile,
// W-frags streamed from L2, per-tile epilogue, in-wave pj reduction.
template<int TSC>
__device__ __forceinline__ void stream_tiles(
    const short* __restrict__ Wf, short* sbuf, float* pjb,
    const float* __restrict__ Wp, const float* __restrict__ bl,
    const short8* xh, const short8* xl,
    int rg, int ts, int q, int r, int lane,
    bool wr_sbuf, float* seam_row)
{
    constexpr int J = 24 / TSC;
    const short8* wfh = (const short8*)Wf + lane;
    const short8* wfl = wfh + (WF2_PL / 8);
    float pj[4][3] = {};
    #pragma unroll
    for (int j = 0; j < J; ++j) {
        int t = ts + j * TSC;
        f32x4 a = {0.f, 0.f, 0.f, 0.f};
        #pragma unroll
        for (int c = 0; c < NCH; ++c) {
            short8 bh = wfh[(c * NT2 + t) * 64];
            short8 bo = wfl[(c * NT2 + t) * 64];
            a = __builtin_amdgcn_mfma_f32_16x16x32_bf16(xh[c], bh, a, 0, 0, 0);
            a = __builtin_amdgcn_mfma_f32_16x16x32_bf16(xh[c], bo, a, 0, 0, 0);
            a = __builtin_amdgcn_mfma_f32_16x16x32_bf16(xl[c], bh, a, 0, 0, 0);
        }
        int n = t * 16 + r;
        bool nok = n < DD;
        float w0 = nok ? Wp[n] : 0.f;
        float w1 = nok ? Wp[DD + n] : 0.f;
        float w2 = nok ? Wp[2 * DD + n] : 0.f;
        float b2 = nok ? 2.f * bl[n] : 0.f;
        float v[4];
        #pragma unroll
        for (int g = 0; g < 4; ++g) {
            float x_ = a[g] + b2; v[g] = x_ > 0.f ? x_ : 0.f;
            pj[g][0] += v[g] * w0; pj[g][1] += v[g] * w1; pj[g][2] += v[g] * w2;
        }
        if (wr_sbuf && n < 304) {
            int sr = rg * 8 + q * 2;
            float sa = v[0] + v[1], sb = v[2] + v[3];
            unsigned short h;
            h = bf16_rne(sa);
            sbuf[sr * SROW_ST + n] = (short)h;
            sbuf[SPLANE_SH + sr * SROW_ST + n] = (short)bf16_rne(sa - bf16_to_f32(h));
            h = bf16_rne(sb);
            sbuf[(sr + 1) * SROW_ST + n] = (short)h;
            sbuf[SPLANE_SH + (sr + 1) * SROW_ST + n] = (short)bf16_rne(sb - bf16_to_f32(h));
        }
        if (seam_row != nullptr && rg == 0 && q == 0 && nok) seam_row[n] = v[0];
    }
    #pragma unroll
    for (int g = 0; g < 4; ++g)
        #pragma unroll
        for (int cc = 0; cc < 3; ++cc) {
            float vv = pj[g][cc];
            vv += __shfl_xor(vv, 1); vv += __shfl_xor(vv, 2);
            vv += __shfl_xor(vv, 4); vv += __shfl_xor(vv, 8);
            pj[g][cc] = vv;
        }
    if (r == 0) {
        #pragma unroll
        for (int g = 0; g < 4; ++g) {
            int row = rg * 16 + q * 4 + g;
            #pragma unroll
            for (int cc = 0; cc < 3; ++cc)
                pjb[(row * TSC + ts) * 3 + cc] = pj[g][cc];
        }
    }
}

// ---------------- Kernel B/C: MODE 1 = levels 2-9 (staged entry, streamed
// rest); MODE 2 = levels 10-12 (pair-gather entry, all streamed).
template<int MODE, int SLEV>
__global__ __launch_bounds__(512, 1) void tree_bc(
    const float* __restrict__ src, const short* __restrict__ Wf,
    const float* __restrict__ bl, const float* __restrict__ Wp,
    const float* __restrict__ bp, float* __restrict__ out,
    float* __restrict__ seam, int l_entry)
{
    __shared__ __align__(16) short wbuf[2 * WB_SH];
    __shared__ __align__(16) short sbuf[2 * SPLANE_SH];
    const int tid = threadIdx.x;
    const int wid = tid >> 6, lane = tid & 63;
    const int r = lane & 15, q = lane >> 4;
    const int blk = blockIdx.x;

    // zero k-pad cols [304,312) of both s planes
    for (int i = tid; i < 64 * 8 * 2; i += 512) {
        int pl = i >> 9, j = i & 511;
        sbuf[pl * SPLANE_SH + (j >> 3) * SROW_ST + 304 + (j & 7)] = 0;
    }

    #pragma unroll 1
    for (int s = 0; s < SLEV; ++s) {
        const int n_l = 128 >> s;

        if (MODE == 1 && s == 0) {
            // ---- staged entry level: x = seam1 pairsum rows (f32)
            f32x4 acc[NT];
            #pragma unroll
            for (int t = 0; t < NT; ++t)
                #pragma unroll
                for (int i = 0; i < 4; ++i) acc[t][i] = 0.f;

            auto stage = [&](int c, int bsel) {
                short* wb = &wbuf[bsel * WB_SH];
                #pragma unroll
                for (int t2i = 0; t2i < 5; ++t2i) {
                    int t2 = wid + t2i * 8;
                    if (t2 < 2 * NT) {
                        int pl = t2 >= NT ? 1 : 0;
                        int ss = t2 - pl * NT;
                        gload_lds16(Wf + (long)pl * WF2_PL + ((long)c * NT2 + ss) * 512 + lane * 8,
                                    &wb[pl * PLANE_SH + ss * 512]);
                    }
                }
            };
            const float* p0 = src + ((long)blk * 128 + wid * 16 + r) * DD;
            f32x4 xc[2], xn[2];
            auto loadx = [&](int c, f32x4* x) {
                int kk = c * 32 + q * 8;
                if (kk + 8 <= DD) {
                    x[0] = *(const f32x4*)(p0 + kk); x[1] = *(const f32x4*)(p0 + kk + 4);
                } else {
                    #pragma unroll
                    for (int i = 0; i < 8; ++i) {
                        int kg = kk + i;
                        x[i >> 2][i & 3] = (kg < DD) ? p0[kg] : 0.f;
                    }
                }
            };
            __syncthreads();
            stage(0, 0);
            loadx(0, xc);
            #pragma unroll 1
            for (int c = 0; c < NCH; ++c) {
                __syncthreads();
                if (c + 1 < NCH) { stage(c + 1, (c + 1) & 1); loadx(c + 1, xn); }
                short8 xhi, xlo;
                #pragma unroll
                for (int i = 0; i < 4; ++i) {
                    unsigned short h; float v;
                    v = xc[0][i]; h = bf16_rne(v); xhi[i]     = (short)h; xlo[i]     = (short)bf16_rne(v - bf16_to_f32(h));
                    v = xc[1][i]; h = bf16_rne(v); xhi[4 + i] = (short)h; xlo[4 + i] = (short)bf16_rne(v - bf16_to_f32(h));
                }
                const short8* bb = (const short8*)&wbuf[(c & 1) * WB_SH] + lane;
                #pragma unroll
                for (int t = 0; t < NT; ++t) {
                    short8 bh = bb[t * 64];
                    short8 bo = bb[1216 + t * 64];
                    acc[t] = __builtin_amdgcn_mfma_f32_16x16x32_bf16(xhi, bh, acc[t], 0, 0, 0);
                    acc[t] = __builtin_amdgcn_mfma_f32_16x16x32_bf16(xhi, bo, acc[t], 0, 0, 0);
                    acc[t] = __builtin_amdgcn_mfma_f32_16x16x32_bf16(xlo, bh, acc[t], 0, 0, 0);
                }
                if (c + 1 < NCH) { xc[0] = xn[0]; xc[1] = xn[1]; }
            }
            __syncthreads();
            float* pjb = (float*)wbuf;
            {
                float pj[4][3] = {};
                #pragma unroll
                for (int t = 0; t < NT; ++t) {
                    int n = t * 16 + r;
                    bool nok = n < DD;
                    float w0 = nok ? Wp[n] : 0.f;
                    float w1 = nok ? Wp[DD + n] : 0.f;
                    float w2 = nok ? Wp[2 * DD + n] : 0.f;
                    float b2 = nok ? 2.f * bl[n] : 0.f;
                    float v[4];
                    #pragma unroll
                    for (int g = 0; g < 4; ++g) {
                        float a = acc[t][g] + b2; v[g] = a > 0.f ? a : 0.f;
                        pj[g][0] += v[g] * w0; pj[g][1] += v[g] * w1; pj[g][2] += v[g] * w2;
                    }
                    {   // pairsum -> sbuf (n in [300,304) writes exact zeros)
                        int sr = wid * 8 + q * 2;
                        float sa = v[0] + v[1], sb = v[2] + v[3];
                        unsigned short h;
                        h = bf16_rne(sa);
                        sbuf[sr * SROW_ST + n] = (short)h;
                        sbuf[SPLANE_SH + sr * SROW_ST + n] = (short)bf16_rne(sa - bf16_to_f32(h));
                        h = bf16_rne(sb);
                        sbuf[(sr + 1) * SROW_ST + n] = (short)h;
                        sbuf[SPLANE_SH + (sr + 1) * SROW_ST + n] = (short)bf16_rne(sb - bf16_to_f32(h));
                    }
                }
                #pragma unroll
                for (int g = 0; g < 4; ++g)
                    #pragma unroll
                    for (int cc = 0; cc < 3; ++cc)
                        pjb[((wid * 16 + q * 4 + g) * 16 + r) * 3 + cc] = pj[g][cc];
            }
            __syncthreads();
            if (tid < 128) {
                const float* base = &pjb[tid * 48];
                float o0 = 0.f, o1 = 0.f, o2 = 0.f;
                #pragma unroll
                for (int rr = 0; rr < 16; ++rr) {
                    o0 += base[rr * 3]; o1 += base[rr * 3 + 1]; o2 += base[rr * 3 + 2];
                }
                out_store(out, l_entry, blk * 128 + tid, o0, o1, o2, bp);
            }
        } else {
            // ---- streamed level
            const int nrg = (n_l >= 16) ? (n_l >> 4) : 1;
            const int lg2 = (nrg == 8) ? 3 : (nrg == 4) ? 2 : (nrg == 2) ? 1 : 0;
            const int tsc = 8 >> lg2;
            const int rg = wid & (nrg - 1);
            const int ts = wid >> lg2;

            __syncthreads();               // prev reducer done; sbuf visible
            short8 xh[10], xl[10];
            if (MODE == 2 && s == 0) {
                const float* pa = src + (long)(2 * (rg * 16 + r)) * DD;
                const float* pb = pa + DD;
                #pragma unroll
                for (int c = 0; c < NCH; ++c) {
                    int kk = c * 32 + q * 8;
                    f32x4 t0, t1;
                    if (kk + 8 <= DD) {
                        t0 = *(const f32x4*)(pa + kk) + *(const f32x4*)(pb + kk);
                        t1 = *(const f32x4*)(pa + kk + 4) + *(const f32x4*)(pb + kk + 4);
                    } else {
                        #pragma unroll
                        for (int i = 0; i < 8; ++i) {
                            int kg = kk + i;
                            float vv = (kg < DD) ? (pa[kg] + pb[kg]) : 0.f;
                            if (i < 4) t0[i] = vv; else t1[i - 4] = vv;
                        }
                    }
                    short8 hh, ll;
                    #pragma unroll
                    for (int i = 0; i < 4; ++i) {
                        unsigned short h; float v;
                        v = t0[i]; h = bf16_rne(v); hh[i]     = (short)h; ll[i]     = (short)bf16_rne(v - bf16_to_f32(h));
                        v = t1[i]; h = bf16_rne(v); hh[4 + i] = (short)h; ll[4 + i] = (short)bf16_rne(v - bf16_to_f32(h));
                    }
                    xh[c] = hh; xl[c] = ll;
                }
            } else {
                int rowA = rg * 16 + r;
                #pragma unroll
                for (int c = 0; c < NCH; ++c) {
                    int kk = c * 32 + q * 8;
                    if (kk + 8 <= SROW_ST) {
                        xh[c] = *(const short8*)&sbuf[rowA * SROW_ST + kk];
                        xl[c] = *(const short8*)&sbuf[SPLANE_SH + rowA * SROW_ST + kk];
                    } else {
                        short8 z = {0, 0, 0, 0, 0, 0, 0, 0};
                        xh[c] = z; xl[c] = z;
                    }
                }
            }
            __syncthreads();               // all x reads done -> sbuf writable

            float* pjb = (float*)wbuf;
            bool wr_sbuf = (s + 1 < SLEV);
            float* seam_row = (s + 1 == SLEV && seam != nullptr)
                                  ? (seam + (size_t)blk * DD) : nullptr;
            switch (tsc) {
                case 1: stream_tiles<1>((const short*)Wf, sbuf, pjb, Wp, bl, xh, xl, rg, ts, q, r, lane, wr_sbuf, seam_row); break;
                case 2: stream_tiles<2>((const short*)Wf, sbuf, pjb, Wp, bl, xh, xl, rg, ts, q, r, lane, wr_sbuf, seam_row); break;
                case 4: stream_tiles<4>((const short*)Wf, sbuf, pjb, Wp, bl, xh, xl, rg, ts, q, r, lane, wr_sbuf, seam_row); break;
                default: stream_tiles<8>((const short*)Wf, sbuf, pjb, Wp, bl, xh, xl, rg, ts, q, r, lane, wr_sbuf, seam_row); break;
            }
            __syncthreads();
            if (tid < n_l) {
                const float* base = pjb + tid * tsc * 3;
                float o0 = 0.f, o1 = 0.f, o2 = 0.f;
                for (int u = 0; u < tsc; ++u) {
                    o0 += base[u * 3]; o1 += base[u * 3 + 1]; o2 += base[u * 3 + 2];
                }
                out_store(out, l_entry + s, blk * n_l + tid, o0, o1, o2, bp);
            }
        }
    }
}

extern "C" void kernel_launch(void* const* d_in, const int* in_sizes, int n_in,
                              void* d_out, int out_size, void* d_ws, size_t ws_size,
                              hipStream_t stream)
{
    const int*   word_ids  = (const int*)d_in[0];    // (32, 4096) int32
    const float* embedding = (const float*)d_in[1];  // (50000, 300) f32
    const float* Wl        = (const float*)d_in[2];  // (300, 300) f32
    const float* bl        = (const float*)d_in[3];  // (300,) f32
    const float* Wp        = (const float*)d_in[4];  // (3, 300) f32
    const float* bp        = (const float*)d_in[5];  // (3,) f32
    float* out = (float*)d_out;

    // ws: Wf (491520 B) | seam1 (32768x300 f32) | seam2 (256x300 f32)
    char* ws = (char*)d_ws;
    short* Wf    = (short*)ws;
    float* seam1 = (float*)(ws + (size_t)2 * WF2_PL * 2);
    float* seam2 = (float*)(ws + (size_t)2 * WF2_PL * 2 + (size_t)32768 * DD * 4);

    split_w<<<(WF2_PL + 255) / 256, 256, 0, stream>>>(Wl, Wf);

    // A: level-0 proj + level 1 (65536 rows, 128/block, 2 blocks/CU)
    tree_a<<<512, 512, 0, stream>>>(embedding, word_ids, Wf, bl, Wp, bp, out, seam1);
    // B: levels 2-9 (32768 level-2 rows, 128/block; staged s0, streamed s1-7)
    tree_bc<1, 8><<<256, 512, 0, stream>>>(seam1, Wf, bl, Wp, bp, out, seam2, 2);
    // C: levels 10-12 (pairs of B's 256 level-9 rows; fully streamed)
    tree_bc<2, 3><<<1, 512, 0, stream>>>(seam2, Wf, bl, Wp, bp, out, nullptr, 10);
}

// Round 5
// 361.357 us; speedup vs baseline: 1.4746x; 1.4746x over previous
//
#include <hip/hip_runtime.h>

#define DD 300
#define NT 19                       // staged n-tiles of 16 (covers 304)
#define NT2 24                      // frag-layout tiles (19 real + 5 zero pad)
#define NCH 10                      // k-chunks of 32
#define PLANE_SH 9728               // shorts per W plane-chunk in LDS: 19*512
#define WB_SH (2 * PLANE_SH)        // one LDS staging buffer (hi+lo) = 19456 shorts
#define WF2_PL (NCH * NT2 * 512)    // shorts per frag-layout plane = 122880
#define SROW_ST 312                 // shorts per s-row (16B aligned)
#define SPLANE_SH (64 * SROW_ST)    // shorts per s plane (64 rows)

typedef __attribute__((ext_vector_type(8))) short short8;
typedef __attribute__((ext_vector_type(4))) float f32x4;

__device__ __forceinline__ unsigned short bf16_rne(float x) {
    union { float f; unsigned u; } v; v.f = x;
    v.u += 0x7FFF + ((v.u >> 16) & 1);
    return (unsigned short)(v.u >> 16);
}
__device__ __forceinline__ float bf16_to_f32(unsigned short h) {
    union { unsigned u; float f; } v; v.u = (unsigned)h << 16;
    return v.f;
}
__device__ __forceinline__ void gload_lds16(const void* g, void* l) {
    __builtin_amdgcn_global_load_lds(
        (const __attribute__((address_space(1))) unsigned*)g,
        (__attribute__((address_space(3))) unsigned*)l, 16, 0, 0);
}

// W -> MFMA-fragment-ordered bf16 hi/lo planes, 24 tiles (19 real + 5 zero):
// Wf[pl][c][t][lane][i] = plane_pl of W[n=t*16+(lane&15)][k=c*32+(lane>>4)*8+i]
__global__ void split_w(const float* __restrict__ Wl, short* __restrict__ Wf) {
    int idx = blockIdx.x * 256 + threadIdx.x;
    if (idx >= WF2_PL) return;
    int i = idx & 7, lane = (idx >> 3) & 63, rest = idx >> 9;
    int t = rest % NT2, c = rest / NT2;
    int n = t * 16 + (lane & 15);
    int k = c * 32 + (lane >> 4) * 8 + i;
    float v = (n < DD && k < DD) ? Wl[n * DD + k] : 0.f;
    unsigned short hi = bf16_rne(v);
    Wf[idx] = (short)hi;
    Wf[idx + WF2_PL] = (short)bf16_rne(v - bf16_to_f32(hi));
}

__device__ __forceinline__ void out_store(float* out, int la, int g_row,
                                          float o0, float o1, float o2,
                                          const float* bp) {
    int lg = 12 - la;
    int offk = 8192 - (8192 >> la);
    int b = g_row >> lg, n2 = g_row & ((1 << lg) - 1);
    float* o = out + ((size_t)b * 8191 + offk + n2) * 3;
    o[0] = o0 + bp[0]; o[1] = o1 + bp[1]; o[2] = o2 + bp[2];
}

// ---------------- Kernel A: level-0 proj + level 1 only. LDS = wbuf only
// (76 KB) -> 2 blocks/CU possible, one block-round. Seam: f32 pairsums.
// launch_bounds(512,2): caps regalloc at 128 VGPR (the body's natural size,
// proven rounds 2/3) WITHOUT the 64-reg spill collapse that (512,4) caused.
__global__ __launch_bounds__(512, 2) void tree_a(
    const float* __restrict__ emb, const int* __restrict__ ids,
    const short* __restrict__ Wf,
    const float* __restrict__ bl, const float* __restrict__ Wp,
    const float* __restrict__ bp, float* __restrict__ out,
    float* __restrict__ seam)
{
    __shared__ __align__(16) short wbuf[2 * WB_SH];
    const int tid = threadIdx.x;
    const int wid = tid >> 6, lane = tid & 63;
    const int r = lane & 15, q = lane >> 4;
    const int blk = blockIdx.x;

    auto stage = [&](int c, int bsel) {
        short* wb = &wbuf[bsel * WB_SH];
        #pragma unroll
        for (int t2i = 0; t2i < 5; ++t2i) {
            int t2 = wid + t2i * 8;
            if (t2 < 2 * NT) {
                int pl = t2 >= NT ? 1 : 0;
                int ss = t2 - pl * NT;
                gload_lds16(Wf + (long)pl * WF2_PL + ((long)c * NT2 + ss) * 512 + lane * 8,
                            &wb[pl * PLANE_SH + ss * 512]);
            }
        }
    };

    const int rowA = wid * 16 + r;
    long mA = (long)blk * 128 + rowA;
    const float* p0 = emb + (long)ids[2 * mA] * DD;
    const float* p1 = emb + (long)ids[2 * mA + 1] * DD;

    float pr[2][3] = {};
    f32x4 acc[NT];
    #pragma unroll
    for (int t = 0; t < NT; ++t)
        #pragma unroll
        for (int i = 0; i < 4; ++i) acc[t][i] = 0.f;

    f32x4 xc[4], xn[4];
    auto loadx = [&](int c, f32x4* x) {
        int kk = c * 32 + q * 8;
        if (kk + 8 <= DD) {
            x[0] = *(const f32x4*)(p0 + kk); x[1] = *(const f32x4*)(p0 + kk + 4);
            x[2] = *(const f32x4*)(p1 + kk); x[3] = *(const f32x4*)(p1 + kk + 4);
        } else {
            #pragma unroll
            for (int i = 0; i < 8; ++i) {
                int kg = kk + i;
                x[i >> 2][i & 3]       = (kg < DD) ? p0[kg] : 0.f;
                x[2 + (i >> 2)][i & 3] = (kg < DD) ? p1[kg] : 0.f;
            }
        }
    };

    stage(0, 0);
    loadx(0, xc);
    #pragma unroll 1
    for (int c = 0; c < NCH; ++c) {
        __syncthreads();
        if (c + 1 < NCH) { stage(c + 1, (c + 1) & 1); loadx(c + 1, xn); }
        f32x4 s0v = xc[0] + xc[2], s1v = xc[1] + xc[3];
        short8 xhi, xlo;
        #pragma unroll
        for (int i = 0; i < 4; ++i) {
            unsigned short h; float v;
            v = s0v[i]; h = bf16_rne(v); xhi[i]     = (short)h; xlo[i]     = (short)bf16_rne(v - bf16_to_f32(h));
            v = s1v[i]; h = bf16_rne(v); xhi[4 + i] = (short)h; xlo[4 + i] = (short)bf16_rne(v - bf16_to_f32(h));
        }
        {   // fused level-0 projection off the in-register gather
            int kk = c * 32 + q * 8;
            #pragma unroll
            for (int i = 0; i < 8; ++i) {
                int kg = kk + i;
                float w0 = (kg < DD) ? Wp[kg] : 0.f;
                float w1 = (kg < DD) ? Wp[DD + kg] : 0.f;
                float w2 = (kg < DD) ? Wp[2 * DD + kg] : 0.f;
                float xa = xc[i >> 2][i & 3];
                float xb = xc[2 + (i >> 2)][i & 3];
                pr[0][0] += xa * w0; pr[0][1] += xa * w1; pr[0][2] += xa * w2;
                pr[1][0] += xb * w0; pr[1][1] += xb * w1; pr[1][2] += xb * w2;
            }
        }
        const short8* bb = (const short8*)&wbuf[(c & 1) * WB_SH] + lane;
        #pragma unroll
        for (int t = 0; t < NT; ++t) {
            short8 bh = bb[t * 64];
            short8 bo = bb[1216 + t * 64];
            acc[t] = __builtin_amdgcn_mfma_f32_16x16x32_bf16(xhi, bh, acc[t], 0, 0, 0);
            acc[t] = __builtin_amdgcn_mfma_f32_16x16x32_bf16(xhi, bo, acc[t], 0, 0, 0);
            acc[t] = __builtin_amdgcn_mfma_f32_16x16x32_bf16(xlo, bh, acc[t], 0, 0, 0);
        }
        if (c + 1 < NCH) {
            #pragma unroll
            for (int i = 0; i < 4; ++i) xc[i] = xn[i];
        }
    }

    __syncthreads();
    float* pjb = (float*)wbuf;
    {
        float pj[4][3] = {};
        #pragma unroll
        for (int t = 0; t < NT; ++t) {
            int n = t * 16 + r;
            bool nok = n < DD;
            float w0 = nok ? Wp[n] : 0.f;
            float w1 = nok ? Wp[DD + n] : 0.f;
            float w2 = nok ? Wp[2 * DD + n] : 0.f;
            float b2 = nok ? 2.f * bl[n] : 0.f;
            float v[4];
            #pragma unroll
            for (int g = 0; g < 4; ++g) {
                float a = acc[t][g] + b2; v[g] = a > 0.f ? a : 0.f;
                pj[g][0] += v[g] * w0; pj[g][1] += v[g] * w1; pj[g][2] += v[g] * w2;
            }
            if (nok) {
                int sr = blk * 64 + wid * 8 + q * 2;
                seam[(size_t)sr * DD + n]       = v[0] + v[1];
                seam[(size_t)(sr + 1) * DD + n] = v[2] + v[3];
            }
        }
        #pragma unroll
        for (int g = 0; g < 4; ++g)
            #pragma unroll
            for (int cc = 0; cc < 3; ++cc)
                pjb[((wid * 16 + q * 4 + g) * 16 + r) * 3 + cc] = pj[g][cc];
    }
    __syncthreads();
    if (tid < 128) {
        const float* base = &pjb[tid * 48];
        float o0 = 0.f, o1 = 0.f, o2 = 0.f;
        #pragma unroll
        for (int rr = 0; rr < 16; ++rr) {
            o0 += base[rr * 3]; o1 += base[rr * 3 + 1]; o2 += base[rr * 3 + 2];
        }
        out_store(out, 1, blk * 128 + tid, o0, o1, o2, bp);
    }
    // level-0 projection finish
    #pragma unroll
    for (int j = 0; j < 2; ++j)
        #pragma unroll
        for (int cc = 0; cc < 3; ++cc) {
            float v = pr[j][cc];
            v += __shfl_xor(v, 16);
            v += __shfl_xor(v, 32);
            pr[j][cc] = v;
        }
    if (q == 0) {
        #pragma unroll
        for (int j = 0; j < 2; ++j) {
            long gr = 2 * mA + j;
            int b = (int)(gr >> 12), n = (int)(gr & 4095);
            float* o = out + ((size_t)b * 8191 + n) * 3;
            o[0] = pr[j][0] + bp[0];
            o[1] = pr[j][1] + bp[1];
            o[2] = pr[j][2] + bp[2];
        }
    }
}

// ---------------- tile-outer streamed level, PAIR-INTERLEAVED: two tiles'
// MFMA chains interleaved (halves exposed dep latency, doubles loads in
// flight). W-frags streamed from L2; per-tile epilogue; in-wave pj reduce.
template<int TSC>
__device__ __forceinline__ void stream_tiles(
    const short* __restrict__ Wf, short* sbuf, float* pjb,
    const float* __restrict__ Wp, const float* __restrict__ bl,
    const short8* xh, const short8* xl,
    int rg, int ts, int q, int r, int lane,
    bool wr_sbuf, float* seam_row)
{
    constexpr int J = 24 / TSC;
    const short8* wfh = (const short8*)Wf + lane;
    const short8* wfl = wfh + (WF2_PL / 8);
    float pj[4][3] = {};

    auto epi = [&](int t, const f32x4& a) {
        int n = t * 16 + r;
        bool nok = n < DD;
        float w0 = nok ? Wp[n] : 0.f;
        float w1 = nok ? Wp[DD + n] : 0.f;
        float w2 = nok ? Wp[2 * DD + n] : 0.f;
        float b2 = nok ? 2.f * bl[n] : 0.f;
        float v[4];
        #pragma unroll
        for (int g = 0; g < 4; ++g) {
            float x_ = a[g] + b2; v[g] = x_ > 0.f ? x_ : 0.f;
            pj[g][0] += v[g] * w0; pj[g][1] += v[g] * w1; pj[g][2] += v[g] * w2;
        }
        if (wr_sbuf && n < 304) {
            int sr = rg * 8 + q * 2;
            float sa = v[0] + v[1], sb = v[2] + v[3];
            unsigned short h;
            h = bf16_rne(sa);
            sbuf[sr * SROW_ST + n] = (short)h;
            sbuf[SPLANE_SH + sr * SROW_ST + n] = (short)bf16_rne(sa - bf16_to_f32(h));
            h = bf16_rne(sb);
            sbuf[(sr + 1) * SROW_ST + n] = (short)h;
            sbuf[SPLANE_SH + (sr + 1) * SROW_ST + n] = (short)bf16_rne(sb - bf16_to_f32(h));
        }
        if (seam_row != nullptr && rg == 0 && q == 0 && nok) seam_row[n] = v[0];
    };

    #pragma unroll
    for (int j = 0; j + 1 < J; j += 2) {
        int t0 = ts + j * TSC, t1 = t0 + TSC;
        f32x4 a0 = {0.f, 0.f, 0.f, 0.f}, a1 = {0.f, 0.f, 0.f, 0.f};
        #pragma unroll
        for (int c = 0; c < NCH; ++c) {
            short8 b0h = wfh[(c * NT2 + t0) * 64];
            short8 b1h = wfh[(c * NT2 + t1) * 64];
            short8 b0o = wfl[(c * NT2 + t0) * 64];
            short8 b1o = wfl[(c * NT2 + t1) * 64];
            a0 = __builtin_amdgcn_mfma_f32_16x16x32_bf16(xh[c], b0h, a0, 0, 0, 0);
            a1 = __builtin_amdgcn_mfma_f32_16x16x32_bf16(xh[c], b1h, a1, 0, 0, 0);
            a0 = __builtin_amdgcn_mfma_f32_16x16x32_bf16(xh[c], b0o, a0, 0, 0, 0);
            a1 = __builtin_amdgcn_mfma_f32_16x16x32_bf16(xh[c], b1o, a1, 0, 0, 0);
            a0 = __builtin_amdgcn_mfma_f32_16x16x32_bf16(xl[c], b0h, a0, 0, 0, 0);
            a1 = __builtin_amdgcn_mfma_f32_16x16x32_bf16(xl[c], b1h, a1, 0, 0, 0);
        }
        epi(t0, a0);
        epi(t1, a1);
    }
    if (J & 1) {
        int t = ts + (J - 1) * TSC;
        f32x4 a = {0.f, 0.f, 0.f, 0.f};
        #pragma unroll
        for (int c = 0; c < NCH; ++c) {
            short8 bh = wfh[(c * NT2 + t) * 64];
            short8 bo = wfl[(c * NT2 + t) * 64];
            a = __builtin_amdgcn_mfma_f32_16x16x32_bf16(xh[c], bh, a, 0, 0, 0);
            a = __builtin_amdgcn_mfma_f32_16x16x32_bf16(xh[c], bo, a, 0, 0, 0);
            a = __builtin_amdgcn_mfma_f32_16x16x32_bf16(xl[c], bh, a, 0, 0, 0);
        }
        epi(t, a);
    }

    #pragma unroll
    for (int g = 0; g < 4; ++g)
        #pragma unroll
        for (int cc = 0; cc < 3; ++cc) {
            float vv = pj[g][cc];
            vv += __shfl_xor(vv, 1); vv += __shfl_xor(vv, 2);
            vv += __shfl_xor(vv, 4); vv += __shfl_xor(vv, 8);
            pj[g][cc] = vv;
        }
    if (r == 0) {
        #pragma unroll
        for (int g = 0; g < 4; ++g) {
            int row = rg * 16 + q * 4 + g;
            #pragma unroll
            for (int cc = 0; cc < 3; ++cc)
                pjb[(row * TSC + ts) * 3 + cc] = pj[g][cc];
        }
    }
}

// ---------------- Kernel B/C: MODE 1 = levels 2-9 (staged entry, streamed
// rest); MODE 2 = levels 10-12 (pair-gather entry, all streamed).
template<int MODE, int SLEV>
__global__ __launch_bounds__(512, 1) void tree_bc(
    const float* __restrict__ src, const short* __restrict__ Wf,
    const float* __restrict__ bl, const float* __restrict__ Wp,
    const float* __restrict__ bp, float* __restrict__ out,
    float* __restrict__ seam, int l_entry)
{
    __shared__ __align__(16) short wbuf[2 * WB_SH];
    __shared__ __align__(16) short sbuf[2 * SPLANE_SH];
    const int tid = threadIdx.x;
    const int wid = tid >> 6, lane = tid & 63;
    const int r = lane & 15, q = lane >> 4;
    const int blk = blockIdx.x;

    // zero k-pad cols [304,312) of both s planes
    for (int i = tid; i < 64 * 8 * 2; i += 512) {
        int pl = i >> 9, j = i & 511;
        sbuf[pl * SPLANE_SH + (j >> 3) * SROW_ST + 304 + (j & 7)] = 0;
    }

    #pragma unroll 1
    for (int s = 0; s < SLEV; ++s) {
        const int n_l = 128 >> s;

        if (MODE == 1 && s == 0) {
            // ---- staged entry level: x = seam1 pairsum rows (f32)
            f32x4 acc[NT];
            #pragma unroll
            for (int t = 0; t < NT; ++t)
                #pragma unroll
                for (int i = 0; i < 4; ++i) acc[t][i] = 0.f;

            auto stage = [&](int c, int bsel) {
                short* wb = &wbuf[bsel * WB_SH];
                #pragma unroll
                for (int t2i = 0; t2i < 5; ++t2i) {
                    int t2 = wid + t2i * 8;
                    if (t2 < 2 * NT) {
                        int pl = t2 >= NT ? 1 : 0;
                        int ss = t2 - pl * NT;
                        gload_lds16(Wf + (long)pl * WF2_PL + ((long)c * NT2 + ss) * 512 + lane * 8,
                                    &wb[pl * PLANE_SH + ss * 512]);
                    }
                }
            };
            const float* p0 = src + ((long)blk * 128 + wid * 16 + r) * DD;
            f32x4 xc[2], xn[2];
            auto loadx = [&](int c, f32x4* x) {
                int kk = c * 32 + q * 8;
                if (kk + 8 <= DD) {
                    x[0] = *(const f32x4*)(p0 + kk); x[1] = *(const f32x4*)(p0 + kk + 4);
                } else {
                    #pragma unroll
                    for (int i = 0; i < 8; ++i) {
                        int kg = kk + i;
                        x[i >> 2][i & 3] = (kg < DD) ? p0[kg] : 0.f;
                    }
                }
            };
            __syncthreads();
            stage(0, 0);
            loadx(0, xc);
            #pragma unroll 1
            for (int c = 0; c < NCH; ++c) {
                __syncthreads();
                if (c + 1 < NCH) { stage(c + 1, (c + 1) & 1); loadx(c + 1, xn); }
                short8 xhi, xlo;
                #pragma unroll
                for (int i = 0; i < 4; ++i) {
                    unsigned short h; float v;
                    v = xc[0][i]; h = bf16_rne(v); xhi[i]     = (short)h; xlo[i]     = (short)bf16_rne(v - bf16_to_f32(h));
                    v = xc[1][i]; h = bf16_rne(v); xhi[4 + i] = (short)h; xlo[4 + i] = (short)bf16_rne(v - bf16_to_f32(h));
                }
                const short8* bb = (const short8*)&wbuf[(c & 1) * WB_SH] + lane;
                #pragma unroll
                for (int t = 0; t < NT; ++t) {
                    short8 bh = bb[t * 64];
                    short8 bo = bb[1216 + t * 64];
                    acc[t] = __builtin_amdgcn_mfma_f32_16x16x32_bf16(xhi, bh, acc[t], 0, 0, 0);
                    acc[t] = __builtin_amdgcn_mfma_f32_16x16x32_bf16(xhi, bo, acc[t], 0, 0, 0);
                    acc[t] = __builtin_amdgcn_mfma_f32_16x16x32_bf16(xlo, bh, acc[t], 0, 0, 0);
                }
                if (c + 1 < NCH) { xc[0] = xn[0]; xc[1] = xn[1]; }
            }
            __syncthreads();
            float* pjb = (float*)wbuf;
            {
                float pj[4][3] = {};
                #pragma unroll
                for (int t = 0; t < NT; ++t) {
                    int n = t * 16 + r;
                    bool nok = n < DD;
                    float w0 = nok ? Wp[n] : 0.f;
                    float w1 = nok ? Wp[DD + n] : 0.f;
                    float w2 = nok ? Wp[2 * DD + n] : 0.f;
                    float b2 = nok ? 2.f * bl[n] : 0.f;
                    float v[4];
                    #pragma unroll
                    for (int g = 0; g < 4; ++g) {
                        float a = acc[t][g] + b2; v[g] = a > 0.f ? a : 0.f;
                        pj[g][0] += v[g] * w0; pj[g][1] += v[g] * w1; pj[g][2] += v[g] * w2;
                    }
                    {   // pairsum -> sbuf (n in [300,304) writes exact zeros)
                        int sr = wid * 8 + q * 2;
                        float sa = v[0] + v[1], sb = v[2] + v[3];
                        unsigned short h;
                        h = bf16_rne(sa);
                        sbuf[sr * SROW_ST + n] = (short)h;
                        sbuf[SPLANE_SH + sr * SROW_ST + n] = (short)bf16_rne(sa - bf16_to_f32(h));
                        h = bf16_rne(sb);
                        sbuf[(sr + 1) * SROW_ST + n] = (short)h;
                        sbuf[SPLANE_SH + (sr + 1) * SROW_ST + n] = (short)bf16_rne(sb - bf16_to_f32(h));
                    }
                }
                #pragma unroll
                for (int g = 0; g < 4; ++g)
                    #pragma unroll
                    for (int cc = 0; cc < 3; ++cc)
                        pjb[((wid * 16 + q * 4 + g) * 16 + r) * 3 + cc] = pj[g][cc];
            }
            __syncthreads();
            if (tid < 128) {
                const float* base = &pjb[tid * 48];
                float o0 = 0.f, o1 = 0.f, o2 = 0.f;
                #pragma unroll
                for (int rr = 0; rr < 16; ++rr) {
                    o0 += base[rr * 3]; o1 += base[rr * 3 + 1]; o2 += base[rr * 3 + 2];
                }
                out_store(out, l_entry, blk * 128 + tid, o0, o1, o2, bp);
            }
        } else {
            // ---- streamed level
            const int nrg = (n_l >= 16) ? (n_l >> 4) : 1;
            const int lg2 = (nrg == 8) ? 3 : (nrg == 4) ? 2 : (nrg == 2) ? 1 : 0;
            const int tsc = 8 >> lg2;
            const int rg = wid & (nrg - 1);
            const int ts = wid >> lg2;

            __syncthreads();               // prev reducer done; sbuf visible
            short8 xh[10], xl[10];
            if (MODE == 2 && s == 0) {
                const float* pa = src + (long)(2 * (rg * 16 + r)) * DD;
                const float* pb = pa + DD;
                #pragma unroll
                for (int c = 0; c < NCH; ++c) {
                    int kk = c * 32 + q * 8;
                    f32x4 t0, t1;
                    if (kk + 8 <= DD) {
                        t0 = *(const f32x4*)(pa + kk) + *(const f32x4*)(pb + kk);
                        t1 = *(const f32x4*)(pa + kk + 4) + *(const f32x4*)(pb + kk + 4);
                    } else {
                        #pragma unroll
                        for (int i = 0; i < 8; ++i) {
                            int kg = kk + i;
                            float vv = (kg < DD) ? (pa[kg] + pb[kg]) : 0.f;
                            if (i < 4) t0[i] = vv; else t1[i - 4] = vv;
                        }
                    }
                    short8 hh, ll;
                    #pragma unroll
                    for (int i = 0; i < 4; ++i) {
                        unsigned short h; float v;
                        v = t0[i]; h = bf16_rne(v); hh[i]     = (short)h; ll[i]     = (short)bf16_rne(v - bf16_to_f32(h));
                        v = t1[i]; h = bf16_rne(v); hh[4 + i] = (short)h; ll[4 + i] = (short)bf16_rne(v - bf16_to_f32(h));
                    }
                    xh[c] = hh; xl[c] = ll;
                }
            } else {
                int rowA = rg * 16 + r;
                #pragma unroll
                for (int c = 0; c < NCH; ++c) {
                    int kk = c * 32 + q * 8;
                    if (kk + 8 <= SROW_ST) {
                        xh[c] = *(const short8*)&sbuf[rowA * SROW_ST + kk];
                        xl[c] = *(const short8*)&sbuf[SPLANE_SH + rowA * SROW_ST + kk];
                    } else {
                        short8 z = {0, 0, 0, 0, 0, 0, 0, 0};
                        xh[c] = z; xl[c] = z;
                    }
                }
            }
            __syncthreads();               // all x reads done -> sbuf writable

            float* pjb = (float*)wbuf;
            bool wr_sbuf = (s + 1 < SLEV);
            float* seam_row = (s + 1 == SLEV && seam != nullptr)
                                  ? (seam + (size_t)blk * DD) : nullptr;
            switch (tsc) {
                case 1: stream_tiles<1>((const short*)Wf, sbuf, pjb, Wp, bl, xh, xl, rg, ts, q, r, lane, wr_sbuf, seam_row); break;
                case 2: stream_tiles<2>((const short*)Wf, sbuf, pjb, Wp, bl, xh, xl, rg, ts, q, r, lane, wr_sbuf, seam_row); break;
                case 4: stream_tiles<4>((const short*)Wf, sbuf, pjb, Wp, bl, xh, xl, rg, ts, q, r, lane, wr_sbuf, seam_row); break;
                default: stream_tiles<8>((const short*)Wf, sbuf, pjb, Wp, bl, xh, xl, rg, ts, q, r, lane, wr_sbuf, seam_row); break;
            }
            __syncthreads();
            if (tid < n_l) {
                const float* base = pjb + tid * tsc * 3;
                float o0 = 0.f, o1 = 0.f, o2 = 0.f;
                for (int u = 0; u < tsc; ++u) {
                    o0 += base[u * 3]; o1 += base[u * 3 + 1]; o2 += base[u * 3 + 2];
                }
                out_store(out, l_entry + s, blk * n_l + tid, o0, o1, o2, bp);
            }
        }
    }
}

extern "C" void kernel_launch(void* const* d_in, const int* in_sizes, int n_in,
                              void* d_out, int out_size, void* d_ws, size_t ws_size,
                              hipStream_t stream)
{
    const int*   word_ids  = (const int*)d_in[0];    // (32, 4096) int32
    const float* embedding = (const float*)d_in[1];  // (50000, 300) f32
    const float* Wl        = (const float*)d_in[2];  // (300, 300) f32
    const float* bl        = (const float*)d_in[3];  // (300,) f32
    const float* Wp        = (const float*)d_in[4];  // (3, 300) f32
    const float* bp        = (const float*)d_in[5];  // (3,) f32
    float* out = (float*)d_out;

    // ws: Wf (491520 B) | seam1 (32768x300 f32) | seam2 (256x300 f32)
    char* ws = (char*)d_ws;
    short* Wf    = (short*)ws;
    float* seam1 = (float*)(ws + (size_t)2 * WF2_PL * 2);
    float* seam2 = (float*)(ws + (size_t)2 * WF2_PL * 2 + (size_t)32768 * DD * 4);

    split_w<<<(WF2_PL + 255) / 256, 256, 0, stream>>>(Wl, Wf);

    // A: level-0 proj + level 1 (65536 rows, 128/block, 2 blocks/CU)
    tree_a<<<512, 512, 0, stream>>>(embedding, word_ids, Wf, bl, Wp, bp, out, seam1);
    // B: levels 2-9 (32768 level-2 rows, 128/block; staged s0, streamed s1-7)
    tree_bc<1, 8><<<256, 512, 0, stream>>>(seam1, Wf, bl, Wp, bp, out, seam2, 2);
    // C: levels 10-12 (pairs of B's 256 level-9 rows; fully streamed)
    tree_bc<2, 3><<<1, 512, 0, stream>>>(seam2, Wf, bl, Wp, bp, out, nullptr, 10);
}

// Round 7
// 300.919 us; speedup vs baseline: 1.7708x; 1.2008x over previous
//
#include <hip/hip_runtime.h>

#define DD 300
#define NT 19                       // staged n-tiles of 16 (covers 304)
#define NT2 24                      // frag-layout tile stride (19 real + 5 pad)
#define NCH 10                      // k-chunks of 32
#define PLANE_SH 9728               // shorts per W plane-chunk in LDS: 19*512
#define WB_SH (2 * PLANE_SH)        // one LDS staging buffer (hi+lo) = 19456 shorts
#define WF2_PL (NCH * NT2 * 512)    // shorts per frag-layout plane = 122880
#define SROW_ST 312                 // shorts per s-row (16B aligned)
#define SPLANE_SH (64 * SROW_ST)    // shorts per s plane (64 rows)

typedef __attribute__((ext_vector_type(8))) short short8;
typedef __attribute__((ext_vector_type(4))) float f32x4;

__device__ __forceinline__ unsigned short bf16_rne(float x) {
    union { float f; unsigned u; } v; v.f = x;
    v.u += 0x7FFF + ((v.u >> 16) & 1);
    return (unsigned short)(v.u >> 16);
}
__device__ __forceinline__ float bf16_to_f32(unsigned short h) {
    union { unsigned u; float f; } v; v.u = (unsigned)h << 16;
    return v.f;
}
__device__ __forceinline__ void gload_lds16(const void* g, void* l) {
    __builtin_amdgcn_global_load_lds(
        (const __attribute__((address_space(1))) unsigned*)g,
        (__attribute__((address_space(3))) unsigned*)l, 16, 0, 0);
}

// W -> MFMA-fragment-ordered bf16 hi/lo planes, 24-tile stride (19 real):
// Wf[pl][c][t][lane][i] = plane_pl of W[n=t*16+(lane&15)][k=c*32+(lane>>4)*8+i]
__global__ void split_w(const float* __restrict__ Wl, short* __restrict__ Wf) {
    int idx = blockIdx.x * 256 + threadIdx.x;
    if (idx >= WF2_PL) return;
    int i = idx & 7, lane = (idx >> 3) & 63, rest = idx >> 9;
    int t = rest % NT2, c = rest / NT2;
    int n = t * 16 + (lane & 15);
    int k = c * 32 + (lane >> 4) * 8 + i;
    float v = (n < DD && k < DD) ? Wl[n * DD + k] : 0.f;
    unsigned short hi = bf16_rne(v);
    Wf[idx] = (short)hi;
    Wf[idx + WF2_PL] = (short)bf16_rne(v - bf16_to_f32(hi));
}

__device__ __forceinline__ void out_store(float* out, int la, int g_row,
                                          float o0, float o1, float o2,
                                          const float* bp) {
    int lg = 12 - la;
    int offk = 8192 - (8192 >> la);
    int b = g_row >> lg, n2 = g_row & ((1 << lg) - 1);
    float* o = out + ((size_t)b * 8191 + offk + n2) * 3;
    o[0] = o0 + bp[0]; o[1] = o1 + bp[1]; o[2] = o2 + bp[2];
}

// ---------------- Kernel A: level-0 proj + level 1 only (proven round-5).
__global__ __launch_bounds__(512, 2) void tree_a(
    const float* __restrict__ emb, const int* __restrict__ ids,
    const short* __restrict__ Wf,
    const float* __restrict__ bl, const float* __restrict__ Wp,
    const float* __restrict__ bp, float* __restrict__ out,
    float* __restrict__ seam)
{
    __shared__ __align__(16) short wbuf[2 * WB_SH];
    const int tid = threadIdx.x;
    const int wid = tid >> 6, lane = tid & 63;
    const int r = lane & 15, q = lane >> 4;
    const int blk = blockIdx.x;

    auto stage = [&](int c, int bsel) {
        short* wb = &wbuf[bsel * WB_SH];
        #pragma unroll
        for (int t2i = 0; t2i < 5; ++t2i) {
            int t2 = wid + t2i * 8;
            if (t2 < 2 * NT) {
                int pl = t2 >= NT ? 1 : 0;
                int ss = t2 - pl * NT;
                gload_lds16(Wf + (long)pl * WF2_PL + ((long)c * NT2 + ss) * 512 + lane * 8,
                            &wb[pl * PLANE_SH + ss * 512]);
            }
        }
    };

    const int rowA = wid * 16 + r;
    long mA = (long)blk * 128 + rowA;
    const float* p0 = emb + (long)ids[2 * mA] * DD;
    const float* p1 = emb + (long)ids[2 * mA + 1] * DD;

    float pr[2][3] = {};
    f32x4 acc[NT];
    #pragma unroll
    for (int t = 0; t < NT; ++t)
        #pragma unroll
        for (int i = 0; i < 4; ++i) acc[t][i] = 0.f;

    f32x4 xc[4], xn[4];
    auto loadx = [&](int c, f32x4* x) {
        int kk = c * 32 + q * 8;
        if (kk + 8 <= DD) {
            x[0] = *(const f32x4*)(p0 + kk); x[1] = *(const f32x4*)(p0 + kk + 4);
            x[2] = *(const f32x4*)(p1 + kk); x[3] = *(const f32x4*)(p1 + kk + 4);
        } else {
            #pragma unroll
            for (int i = 0; i < 8; ++i) {
                int kg = kk + i;
                x[i >> 2][i & 3]       = (kg < DD) ? p0[kg] : 0.f;
                x[2 + (i >> 2)][i & 3] = (kg < DD) ? p1[kg] : 0.f;
            }
        }
    };

    stage(0, 0);
    loadx(0, xc);
    #pragma unroll 1
    for (int c = 0; c < NCH; ++c) {
        __syncthreads();
        if (c + 1 < NCH) { stage(c + 1, (c + 1) & 1); loadx(c + 1, xn); }
        f32x4 s0v = xc[0] + xc[2], s1v = xc[1] + xc[3];
        short8 xhi, xlo;
        #pragma unroll
        for (int i = 0; i < 4; ++i) {
            unsigned short h; float v;
            v = s0v[i]; h = bf16_rne(v); xhi[i]     = (short)h; xlo[i]     = (short)bf16_rne(v - bf16_to_f32(h));
            v = s1v[i]; h = bf16_rne(v); xhi[4 + i] = (short)h; xlo[4 + i] = (short)bf16_rne(v - bf16_to_f32(h));
        }
        {
            int kk = c * 32 + q * 8;
            #pragma unroll
            for (int i = 0; i < 8; ++i) {
                int kg = kk + i;
                float w0 = (kg < DD) ? Wp[kg] : 0.f;
                float w1 = (kg < DD) ? Wp[DD + kg] : 0.f;
                float w2 = (kg < DD) ? Wp[2 * DD + kg] : 0.f;
                float xa = xc[i >> 2][i & 3];
                float xb = xc[2 + (i >> 2)][i & 3];
                pr[0][0] += xa * w0; pr[0][1] += xa * w1; pr[0][2] += xa * w2;
                pr[1][0] += xb * w0; pr[1][1] += xb * w1; pr[1][2] += xb * w2;
            }
        }
        const short8* bb = (const short8*)&wbuf[(c & 1) * WB_SH] + lane;
        #pragma unroll
        for (int t = 0; t < NT; ++t) {
            short8 bh = bb[t * 64];
            short8 bo = bb[1216 + t * 64];
            acc[t] = __builtin_amdgcn_mfma_f32_16x16x32_bf16(xhi, bh, acc[t], 0, 0, 0);
            acc[t] = __builtin_amdgcn_mfma_f32_16x16x32_bf16(xhi, bo, acc[t], 0, 0, 0);
            acc[t] = __builtin_amdgcn_mfma_f32_16x16x32_bf16(xlo, bh, acc[t], 0, 0, 0);
        }
        if (c + 1 < NCH) {
            #pragma unroll
            for (int i = 0; i < 4; ++i) xc[i] = xn[i];
        }
    }

    __syncthreads();
    float* pjb = (float*)wbuf;
    {
        float pj[4][3] = {};
        #pragma unroll
        for (int t = 0; t < NT; ++t) {
            int n = t * 16 + r;
            bool nok = n < DD;
            float w0 = nok ? Wp[n] : 0.f;
            float w1 = nok ? Wp[DD + n] : 0.f;
            float w2 = nok ? Wp[2 * DD + n] : 0.f;
            float b2 = nok ? 2.f * bl[n] : 0.f;
            float v[4];
            #pragma unroll
            for (int g = 0; g < 4; ++g) {
                float a = acc[t][g] + b2; v[g] = a > 0.f ? a : 0.f;
                pj[g][0] += v[g] * w0; pj[g][1] += v[g] * w1; pj[g][2] += v[g] * w2;
            }
            if (nok) {
                int sr = blk * 64 + wid * 8 + q * 2;
                seam[(size_t)sr * DD + n]       = v[0] + v[1];
                seam[(size_t)(sr + 1) * DD + n] = v[2] + v[3];
            }
        }
        #pragma unroll
        for (int g = 0; g < 4; ++g)
            #pragma unroll
            for (int cc = 0; cc < 3; ++cc)
                pjb[((wid * 16 + q * 4 + g) * 16 + r) * 3 + cc] = pj[g][cc];
    }
    __syncthreads();
    if (tid < 128) {
        const float* base = &pjb[tid * 48];
        float o0 = 0.f, o1 = 0.f, o2 = 0.f;
        #pragma unroll
        for (int rr = 0; rr < 16; ++rr) {
            o0 += base[rr * 3]; o1 += base[rr * 3 + 1]; o2 += base[rr * 3 + 2];
        }
        out_store(out, 1, blk * 128 + tid, o0, o1, o2, bp);
    }
    #pragma unroll
    for (int j = 0; j < 2; ++j)
        #pragma unroll
        for (int cc = 0; cc < 3; ++cc) {
            float v = pr[j][cc];
            v += __shfl_xor(v, 16);
            v += __shfl_xor(v, 32);
            pr[j][cc] = v;
        }
    if (q == 0) {
        #pragma unroll
        for (int j = 0; j < 2; ++j) {
            long gr = 2 * mA + j;
            int b = (int)(gr >> 12), n = (int)(gr & 4095);
            float* o = out + ((size_t)b * 8191 + n) * 3;
            o[0] = pr[j][0] + bp[0];
            o[1] = pr[j][1] + bp[1];
            o[2] = pr[j][2] + bp[2];
        }
    }
}

// ---------------- streamed level, WAVE-OWNS-TILES (n_l <= 64 ONLY: sbuf
// holds 64 pairsum rows/plane). Wave w owns tiles {w, w+8, w+16}<19 and
// loops all rowgroups against each B-frag -> each B-frag read from L2 once
// per block per level; no pad tiles. Phase 1 (MFMA, sbuf reads) | barrier |
// phase 2 (epilogue, sbuf writes + pjb) | barrier.
template<int NRG>
__device__ __forceinline__ void stream_level(
    const short* __restrict__ Wf, short* __restrict__ sbuf, float* __restrict__ pjb,
    const float* __restrict__ Wp, const float* __restrict__ bl,
    int wid, int lane, int rgbase, bool wr_sbuf, float* seam_row)
{
    const int r = lane & 15, q = lane >> 4;
    const int ntl = (wid < 3) ? 3 : 2;
    const int t0 = wid, t1 = wid + 8, t2 = wid + 16;

    const short8* wfh = (const short8*)Wf + lane;
    const short8* wfl = wfh + (WF2_PL / 8);
    const short8 z = {0, 0, 0, 0, 0, 0, 0, 0};

    f32x4 acc[3][NRG];
    #pragma unroll
    for (int j = 0; j < 3; ++j)
        #pragma unroll
        for (int g = 0; g < NRG; ++g)
            #pragma unroll
            for (int i = 0; i < 4; ++i) acc[j][g][i] = 0.f;

    short8 bh0c = wfh[t0 * 64], bo0c = wfl[t0 * 64];
    short8 bh1c = wfh[t1 * 64], bo1c = wfl[t1 * 64];
    short8 bh2c = z, bo2c = z;
    if (ntl == 3) { bh2c = wfh[t2 * 64]; bo2c = wfl[t2 * 64]; }

    #pragma unroll 1
    for (int c = 0; c < NCH; ++c) {
        short8 bh0n = z, bo0n = z, bh1n = z, bo1n = z, bh2n = z, bo2n = z;
        if (c + 1 < NCH) {
            bh0n = wfh[((c + 1) * NT2 + t0) * 64]; bo0n = wfl[((c + 1) * NT2 + t0) * 64];
            bh1n = wfh[((c + 1) * NT2 + t1) * 64]; bo1n = wfl[((c + 1) * NT2 + t1) * 64];
            if (ntl == 3) { bh2n = wfh[((c + 1) * NT2 + t2) * 64]; bo2n = wfl[((c + 1) * NT2 + t2) * 64]; }
        }
        int kk = c * 32 + q * 8;
        #pragma unroll
        for (int rg = 0; rg < NRG; ++rg) {
            short8 xh = z, xl = z;
            if (kk + 8 <= SROW_ST) {
                int row = (rgbase + rg) * 16 + r;
                xh = *(const short8*)&sbuf[row * SROW_ST + kk];
                xl = *(const short8*)&sbuf[SPLANE_SH + row * SROW_ST + kk];
            }
            acc[0][rg] = __builtin_amdgcn_mfma_f32_16x16x32_bf16(xh, bh0c, acc[0][rg], 0, 0, 0);
            acc[0][rg] = __builtin_amdgcn_mfma_f32_16x16x32_bf16(xh, bo0c, acc[0][rg], 0, 0, 0);
            acc[0][rg] = __builtin_amdgcn_mfma_f32_16x16x32_bf16(xl, bh0c, acc[0][rg], 0, 0, 0);
            acc[1][rg] = __builtin_amdgcn_mfma_f32_16x16x32_bf16(xh, bh1c, acc[1][rg], 0, 0, 0);
            acc[1][rg] = __builtin_amdgcn_mfma_f32_16x16x32_bf16(xh, bo1c, acc[1][rg], 0, 0, 0);
            acc[1][rg] = __builtin_amdgcn_mfma_f32_16x16x32_bf16(xl, bh1c, acc[1][rg], 0, 0, 0);
            if (ntl == 3) {
                acc[2][rg] = __builtin_amdgcn_mfma_f32_16x16x32_bf16(xh, bh2c, acc[2][rg], 0, 0, 0);
                acc[2][rg] = __builtin_amdgcn_mfma_f32_16x16x32_bf16(xh, bo2c, acc[2][rg], 0, 0, 0);
                acc[2][rg] = __builtin_amdgcn_mfma_f32_16x16x32_bf16(xl, bh2c, acc[2][rg], 0, 0, 0);
            }
        }
        if (c + 1 < NCH) {
            bh0c = bh0n; bo0c = bo0n; bh1c = bh1n; bo1c = bo1n; bh2c = bh2n; bo2c = bo2n;
        }
    }

    __syncthreads();                 // all sbuf x-reads done -> sbuf writable

    float pj[NRG][4][3];
    #pragma unroll
    for (int rg = 0; rg < NRG; ++rg)
        #pragma unroll
        for (int g = 0; g < 4; ++g)
            #pragma unroll
            for (int cc = 0; cc < 3; ++cc) pj[rg][g][cc] = 0.f;

    #pragma unroll
    for (int j = 0; j < 3; ++j) {
        if (j >= ntl) continue;
        int t = (j == 0) ? t0 : (j == 1) ? t1 : t2;
        int n = t * 16 + r;
        bool nok = n < DD;
        float w0 = nok ? Wp[n] : 0.f;
        float w1 = nok ? Wp[DD + n] : 0.f;
        float w2 = nok ? Wp[2 * DD + n] : 0.f;
        float b2 = nok ? 2.f * bl[n] : 0.f;
        #pragma unroll
        for (int rg = 0; rg < NRG; ++rg) {
            float v[4];
            #pragma unroll
            for (int g = 0; g < 4; ++g) {
                float a = acc[j][rg][g] + b2; v[g] = a > 0.f ? a : 0.f;
                pj[rg][g][0] += v[g] * w0; pj[rg][g][1] += v[g] * w1; pj[rg][g][2] += v[g] * w2;
            }
            if (wr_sbuf) {
                int sr = (rgbase + rg) * 8 + q * 2;
                float sa = v[0] + v[1], sb = v[2] + v[3];
                unsigned short h;
                h = bf16_rne(sa);
                sbuf[sr * SROW_ST + n] = (short)h;
                sbuf[SPLANE_SH + sr * SROW_ST + n] = (short)bf16_rne(sa - bf16_to_f32(h));
                h = bf16_rne(sb);
                sbuf[(sr + 1) * SROW_ST + n] = (short)h;
                sbuf[SPLANE_SH + (sr + 1) * SROW_ST + n] = (short)bf16_rne(sb - bf16_to_f32(h));
            }
            if (seam_row != nullptr && (rgbase + rg) == 0 && q == 0 && nok) seam_row[n] = v[0];
        }
    }
    #pragma unroll
    for (int rg = 0; rg < NRG; ++rg)
        #pragma unroll
        for (int g = 0; g < 4; ++g)
            #pragma unroll
            for (int cc = 0; cc < 3; ++cc) {
                float vv = pj[rg][g][cc];
                vv += __shfl_xor(vv, 1); vv += __shfl_xor(vv, 2);
                vv += __shfl_xor(vv, 4); vv += __shfl_xor(vv, 8);
                pj[rg][g][cc] = vv;
            }
    if (r == 0) {
        #pragma unroll
        for (int rg = 0; rg < NRG; ++rg)
            #pragma unroll
            for (int g = 0; g < 4; ++g) {
                int row = (rgbase + rg) * 16 + q * 4 + g;
                #pragma unroll
                for (int cc = 0; cc < 3; ++cc)
                    pjb[(row * 8 + wid) * 3 + cc] = pj[rg][g][cc];
            }
    }
    __syncthreads();                 // pjb ready for reducer
}

// ---------------- Kernel B/C: staged entry level (128 rows; MODE 1 = direct
// rows from src, MODE 2 = pairsum of src rows 2m,2m+1), then streamed levels
// (wave-owns-tiles; n_l <= 64 always, so sbuf's 64-row planes suffice).
template<int MODE, int SLEV>
__global__ __launch_bounds__(512, 1) void tree_bc(
    const float* __restrict__ src, const short* __restrict__ Wf,
    const float* __restrict__ bl, const float* __restrict__ Wp,
    const float* __restrict__ bp, float* __restrict__ out,
    float* __restrict__ seam, int l_entry)
{
    __shared__ __align__(16) short wbuf[2 * WB_SH];
    __shared__ __align__(16) short sbuf[2 * SPLANE_SH];
    const int tid = threadIdx.x;
    const int wid = tid >> 6, lane = tid & 63;
    const int r = lane & 15, q = lane >> 4;
    const int blk = blockIdx.x;

    // zero k-pad cols [304,312) of both s planes
    for (int i = tid; i < 64 * 8 * 2; i += 512) {
        int pl = i >> 9, j = i & 511;
        sbuf[pl * SPLANE_SH + (j >> 3) * SROW_ST + 304 + (j & 7)] = 0;
    }
    __syncthreads();

    #pragma unroll 1
    for (int s = 0; s < SLEV; ++s) {
        const int n_l = 128 >> s;
        const int la = l_entry + s;
        float* pjb = (float*)wbuf;
        const bool wr = (s + 1 < SLEV);
        float* seam_row = (s + 1 == SLEV && seam != nullptr)
                              ? (seam + (size_t)blk * DD) : nullptr;

        if (s == 0) {
            // ---- staged entry level (LDS multicast; 8 rowgroups need it)
            f32x4 acc[NT];
            #pragma unroll
            for (int t = 0; t < NT; ++t)
                #pragma unroll
                for (int i = 0; i < 4; ++i) acc[t][i] = 0.f;

            auto stage = [&](int c, int bsel) {
                short* wb = &wbuf[bsel * WB_SH];
                #pragma unroll
                for (int t2i = 0; t2i < 5; ++t2i) {
                    int t2 = wid + t2i * 8;
                    if (t2 < 2 * NT) {
                        int pl = t2 >= NT ? 1 : 0;
                        int ss = t2 - pl * NT;
                        gload_lds16(Wf + (long)pl * WF2_PL + ((long)c * NT2 + ss) * 512 + lane * 8,
                                    &wb[pl * PLANE_SH + ss * 512]);
                    }
                }
            };
            const float* p0;
            const float* p1 = nullptr;
            if (MODE == 1) {
                p0 = src + ((long)blk * 128 + wid * 16 + r) * DD;
            } else {
                p0 = src + (long)(2 * (wid * 16 + r)) * DD;   // blk == 0
                p1 = p0 + DD;
            }
            f32x4 xc[2], xn[2];
            auto loadx = [&](int c, f32x4* x) {
                int kk = c * 32 + q * 8;
                if (kk + 8 <= DD) {
                    x[0] = *(const f32x4*)(p0 + kk); x[1] = *(const f32x4*)(p0 + kk + 4);
                    if (MODE == 2) {
                        x[0] += *(const f32x4*)(p1 + kk); x[1] += *(const f32x4*)(p1 + kk + 4);
                    }
                } else {
                    #pragma unroll
                    for (int i = 0; i < 8; ++i) {
                        int kg = kk + i;
                        float vv = 0.f;
                        if (kg < DD) {
                            vv = p0[kg];
                            if (MODE == 2) vv += p1[kg];
                        }
                        x[i >> 2][i & 3] = vv;
                    }
                }
            };
            stage(0, 0);
            loadx(0, xc);
            #pragma unroll 1
            for (int c = 0; c < NCH; ++c) {
                __syncthreads();
                if (c + 1 < NCH) { stage(c + 1, (c + 1) & 1); loadx(c + 1, xn); }
                short8 xhi, xlo;
                #pragma unroll
                for (int i = 0; i < 4; ++i) {
                    unsigned short h; float v;
                    v = xc[0][i]; h = bf16_rne(v); xhi[i]     = (short)h; xlo[i]     = (short)bf16_rne(v - bf16_to_f32(h));
                    v = xc[1][i]; h = bf16_rne(v); xhi[4 + i] = (short)h; xlo[4 + i] = (short)bf16_rne(v - bf16_to_f32(h));
                }
                const short8* bb = (const short8*)&wbuf[(c & 1) * WB_SH] + lane;
                #pragma unroll
                for (int t = 0; t < NT; ++t) {
                    short8 bh = bb[t * 64];
                    short8 bo = bb[1216 + t * 64];
                    acc[t] = __builtin_amdgcn_mfma_f32_16x16x32_bf16(xhi, bh, acc[t], 0, 0, 0);
                    acc[t] = __builtin_amdgcn_mfma_f32_16x16x32_bf16(xhi, bo, acc[t], 0, 0, 0);
                    acc[t] = __builtin_amdgcn_mfma_f32_16x16x32_bf16(xlo, bh, acc[t], 0, 0, 0);
                }
                if (c + 1 < NCH) { xc[0] = xn[0]; xc[1] = xn[1]; }
            }
            __syncthreads();
            {
                float pj[4][3] = {};
                #pragma unroll
                for (int t = 0; t < NT; ++t) {
                    int n = t * 16 + r;
                    bool nok = n < DD;
                    float w0 = nok ? Wp[n] : 0.f;
                    float w1 = nok ? Wp[DD + n] : 0.f;
                    float w2 = nok ? Wp[2 * DD + n] : 0.f;
                    float b2 = nok ? 2.f * bl[n] : 0.f;
                    float v[4];
                    #pragma unroll
                    for (int g = 0; g < 4; ++g) {
                        float a = acc[t][g] + b2; v[g] = a > 0.f ? a : 0.f;
                        pj[g][0] += v[g] * w0; pj[g][1] += v[g] * w1; pj[g][2] += v[g] * w2;
                    }
                    {   // pairsum -> sbuf (n in [300,304) writes exact zeros)
                        int sr = wid * 8 + q * 2;
                        float sa = v[0] + v[1], sb = v[2] + v[3];
                        unsigned short h;
                        h = bf16_rne(sa);
                        sbuf[sr * SROW_ST + n] = (short)h;
                        sbuf[SPLANE_SH + sr * SROW_ST + n] = (short)bf16_rne(sa - bf16_to_f32(h));
                        h = bf16_rne(sb);
                        sbuf[(sr + 1) * SROW_ST + n] = (short)h;
                        sbuf[SPLANE_SH + (sr + 1) * SROW_ST + n] = (short)bf16_rne(sb - bf16_to_f32(h));
                    }
                }
                #pragma unroll
                for (int g = 0; g < 4; ++g)
                    #pragma unroll
                    for (int cc = 0; cc < 3; ++cc)
                        pjb[((wid * 16 + q * 4 + g) * 16 + r) * 3 + cc] = pj[g][cc];
            }
            __syncthreads();
            if (tid < 128) {
                const float* base = &pjb[tid * 48];
                float o0 = 0.f, o1 = 0.f, o2 = 0.f;
                #pragma unroll
                for (int rr = 0; rr < 16; ++rr) {
                    o0 += base[rr * 3]; o1 += base[rr * 3 + 1]; o2 += base[rr * 3 + 2];
                }
                out_store(out, la, blk * 128 + tid, o0, o1, o2, bp);
            }
        } else {
            // ---- streamed level (wave-owns-tiles; n_l <= 64)
            if (n_l == 64) {
                stream_level<4>((const short*)Wf, sbuf, pjb, Wp, bl, wid, lane, 0, wr, seam_row);
            } else if (n_l == 32) {
                stream_level<2>((const short*)Wf, sbuf, pjb, Wp, bl, wid, lane, 0, wr, seam_row);
            } else {
                stream_level<1>((const short*)Wf, sbuf, pjb, Wp, bl, wid, lane, 0, wr, seam_row);
            }
            if (tid < n_l) {
                float o0 = 0.f, o1 = 0.f, o2 = 0.f;
                #pragma unroll
                for (int w = 0; w < 8; ++w) {
                    const float* p = &pjb[(tid * 8 + w) * 3];
                    o0 += p[0]; o1 += p[1]; o2 += p[2];
                }
                out_store(out, la, blk * n_l + tid, o0, o1, o2, bp);
            }
        }
    }
}

extern "C" void kernel_launch(void* const* d_in, const int* in_sizes, int n_in,
                              void* d_out, int out_size, void* d_ws, size_t ws_size,
                              hipStream_t stream)
{
    const int*   word_ids  = (const int*)d_in[0];    // (32, 4096) int32
    const float* embedding = (const float*)d_in[1];  // (50000, 300) f32
    const float* Wl        = (const float*)d_in[2];  // (300, 300) f32
    const float* bl        = (const float*)d_in[3];  // (300,) f32
    const float* Wp        = (const float*)d_in[4];  // (3, 300) f32
    const float* bp        = (const float*)d_in[5];  // (3,) f32
    float* out = (float*)d_out;

    // ws: Wf (491520 B) | seam1 (32768x300 f32) | seam2 (256x300 f32)
    char* ws = (char*)d_ws;
    short* Wf    = (short*)ws;
    float* seam1 = (float*)(ws + (size_t)2 * WF2_PL * 2);
    float* seam2 = (float*)(ws + (size_t)2 * WF2_PL * 2 + (size_t)32768 * DD * 4);

    split_w<<<(WF2_PL + 255) / 256, 256, 0, stream>>>(Wl, Wf);

    // A: level-0 proj + level 1 (65536 rows, 128/block, 2 blocks/CU)
    tree_a<<<512, 512, 0, stream>>>(embedding, word_ids, Wf, bl, Wp, bp, out, seam1);
    // B: levels 2-9 (32768 level-2 rows, 128/block; staged s0, streamed s1-7)
    tree_bc<1, 8><<<256, 512, 0, stream>>>(seam1, Wf, bl, Wp, bp, out, seam2, 2);
    // C: levels 10-12 (staged pairsum entry off seam2, then streamed)
    tree_bc<2, 3><<<1, 512, 0, stream>>>(seam2, Wf, bl, Wp, bp, out, nullptr, 10);
}